// Round 6
// baseline (52.783 us; speedup 1.0000x reference)
//
#include <hip/hip_runtime.h>

typedef unsigned int uint;
typedef unsigned char u8;

// Problem constants (from setup_inputs)
#define B_     2
#define C_     16
#define H_     66
#define W_     66
#define O_     64
#define CKK    144
#define NCH    36          // CKK/4
#define DIM    64          // output spatial
#define L_     4096        // DIM*DIM
#define N_     8192        // B_*L_
#define PLANE  524288      // N_*O_  (elements between (c,s) planes of rand_idx)
#define TSTR   1024        // u8 table row stride (pow2 addressing)
#define TROWS  54          // row 0 = zeros (yp<8 case), rows 1..53 = ptbl rows 8..60

// dot4: sum of the 4 bytes of (xv & mask)  == dot(Xq_chunk, wmask)
__device__ __forceinline__ uint dot4(uint xv, uint m) {
#if __has_builtin(__builtin_amdgcn_sad_u8)
    return __builtin_amdgcn_sad_u8(xv & m, 0u, 0u);   // full-rate byte-sum
#else
    return ((xv & m) * 0x01010101u) >> 24;
#endif
}

// prefetch group: 4 chunks x 2 signs, one dword per lane per load (256B/wave)
__device__ __forceinline__ void loadg(int2 (&bf)[4],
                                      const int* __restrict__ rpP,
                                      const int* __restrict__ rpM, int c0) {
#pragma unroll
    for (int j = 0; j < 4; ++j) {
        bf[j].x = rpP[(c0 + j) * (2 * PLANE)];
        bf[j].y = rpM[(c0 + j) * (2 * PLANE)];
    }
}

// consume group: 2 clamped u8 gathers per chunk, integer accumulate
__device__ __forceinline__ void procg(const int2 (&bf)[4],
                                      const uint*  __restrict__ xrow,
                                      const uint2* __restrict__ wrow,   // &s_w2[o]
                                      const u8*    __restrict__ tb,     // tbl - 7*TSTR
                                      int c0, uint& sumP, uint& sumM) {
#pragma unroll
    for (int j = 0; j < 4; ++j) {
        int c = c0 + j;
        uint  xv = xrow[c];               // wave-uniform broadcast
        uint2 m  = wrow[c * O_];          // ds_read_b64, 512B/wave
        uint rP = dot4(xv, m.x);
        uint rM = dot4(xv, m.y);
        rP = rP < 7u ? 7u : rP;           // yp<8 -> row 7 -> zero row of tb
        rM = rM < 7u ? 7u : rM;
        sumP += tb[(rP << 10) + bf[j].x];
        sumM += tb[(rM << 10) + bf[j].y];
    }
}

__launch_bounds__(1024, 8)   // 8 waves/EU => 2 blocks/CU, forces VGPR <= 64
__global__ void k_fused(const float* __restrict__ x,
                        const float* __restrict__ wgt,
                        const float* __restrict__ cbias,
                        const float* __restrict__ pmin,
                        const float* __restrict__ pmax,
                        const float* __restrict__ ptbl,
                        const int*   __restrict__ ridx,
                        float* __restrict__ out) {
    __shared__ uint2 s_w2[NCH * O_];                 // 18,432 B  [c][o]
    __shared__ uint  s_xq[16 * NCH];                 //  2,304 B
    __shared__ float s_bias[O_];                     //    256 B
    __shared__ __align__(16) u8 tbl[TROWS * TSTR];   // 55,296 B
    // total 76,288 B -> 2 blocks/CU fit in 160 KiB

    const int tid = threadIdx.x;
    const float mn = pmin[0];
    const float sc = pmax[0] - mn;

    // ---- Phase 0a: zero row 0 of the u8 table ----
    {
        uint4 z; z.x = z.y = z.z = z.w = 0u;
        uint4* zp = (uint4*)tbl;
        if (tid < TSTR / 16) zp[tid] = z;
    }
    // ---- Phase 0b: ptbl rows 8..60 -> u8 rows 1..53 (val = rint(v*255)) ----
    for (int q = tid; q < 53 * 250; q += 1024) {     // 250 float4 per source row
        int r = q / 250, k = q - r * 250;
        float4 v = *(const float4*)(ptbl + (8 + r) * 1000 + k * 4);
        uint b0 = (uint)rintf(v.x * 255.f), b1 = (uint)rintf(v.y * 255.f);
        uint b2 = (uint)rintf(v.z * 255.f), b3 = (uint)rintf(v.w * 255.f);
        *(uint*)(tbl + (r + 1) * TSTR + k * 4) = b0 | (b1 << 8) | (b2 << 16) | (b3 << 24);
    }
    // ---- Phase 0c: ternary weight masks [c][o] as uint2 ----
    for (int q = tid; q < NCH * O_; q += 1024) {
        int c = q >> 6, oo = q & 63;
        float4 v = *(const float4*)(wgt + oo * CKK + c * 4);
        uint pm = 0, nm = 0;
        if (v.x > 0.0f) pm |= 0x000000FFu; else if (v.x < 0.0f) nm |= 0x000000FFu;
        if (v.y > 0.0f) pm |= 0x0000FF00u; else if (v.y < 0.0f) nm |= 0x0000FF00u;
        if (v.z > 0.0f) pm |= 0x00FF0000u; else if (v.z < 0.0f) nm |= 0x00FF0000u;
        if (v.w > 0.0f) pm |= 0xFF000000u; else if (v.w < 0.0f) nm |= 0xFF000000u;
        s_w2[q] = make_uint2(pm, nm);
    }
    // ---- Phase 0d: quantize this tile's 16 patches ----
    if (tid < 16 * NCH) {
        int nl2 = tid / NCH;
        int c2  = tid - nl2 * NCH;
        int n2  = blockIdx.x * 16 + nl2;
        int b2 = n2 >> 12, l2 = n2 & (L_ - 1);
        int h2 = l2 >> 6,  w2 = l2 & (DIM - 1);
        uint packed = 0;
#pragma unroll
        for (int k = 0; k < 4; ++k) {
            int j  = c2 * 4 + k;
            int ci = j / 9;
            int r2 = j - ci * 9;
            int kh = r2 / 3;
            int kw = r2 - kh * 3;
            float v = x[((b2 * C_ + ci) * H_ + (h2 + kh)) * W_ + (w2 + kw)];
            float t2 = (v - mn) / sc * 15.0f;                 // jax f32 op order
            float q = fminf(fmaxf(rintf(t2), 0.0f), 15.0f);
            packed |= ((uint)q) << (8 * k);
        }
        s_xq[tid] = packed;
    }
    // ---- Phase 0e: bias from wgt (threads 0..63) ----
    if (tid < O_) {
        int sw = 0;
        for (int j = 0; j < CKK; ++j) {
            float v = wgt[tid * CKK + j];
            sw += (v > 0.0f) - (v < 0.0f);
        }
        s_bias[tid] = mn * (float)sw + cbias[tid];
    }
    __syncthreads();

    // ---- main: wave = one n, lane = one o; 2-group ping-pong prefetch ----
    const int o  = tid & 63;
    const int wv = tid >> 6;                 // 0..15 : n within tile
    const int n  = blockIdx.x * 16 + wv;
    const int* rpP = ridx + n * O_ + o;      // sign+ plane base
    const int* rpM = rpP + PLANE;            // sign- plane base
    const uint*  xrow = &s_xq[wv * NCH];
    const uint2* wrow = &s_w2[o];
    const u8*    tb   = tbl - 7 * TSTR;      // rowm=max(yp,7): 7 -> zero row

    uint sumP = 0, sumM = 0;
    int2 A[4], Bb[4];
    loadg(A,  rpP, rpM, 0);
    loadg(Bb, rpP, rpM, 4);

    procg(A,  xrow, wrow, tb,  0, sumP, sumM); loadg(A,  rpP, rpM,  8);
    procg(Bb, xrow, wrow, tb,  4, sumP, sumM); loadg(Bb, rpP, rpM, 12);
    procg(A,  xrow, wrow, tb,  8, sumP, sumM); loadg(A,  rpP, rpM, 16);
    procg(Bb, xrow, wrow, tb, 12, sumP, sumM); loadg(Bb, rpP, rpM, 20);
    procg(A,  xrow, wrow, tb, 16, sumP, sumM); loadg(A,  rpP, rpM, 24);
    procg(Bb, xrow, wrow, tb, 20, sumP, sumM); loadg(Bb, rpP, rpM, 28);
    procg(A,  xrow, wrow, tb, 24, sumP, sumM); loadg(A,  rpP, rpM, 32);
    procg(Bb, xrow, wrow, tb, 28, sumP, sumM);
    procg(A,  xrow, wrow, tb, 32, sumP, sumM);

    // ---- epilogue: dequant (x 1/255), scale, bias ----
    float f = (float)((int)sumP - (int)sumM);
    out[((n >> 12) * O_ + o) * L_ + (n & (L_ - 1))] =
        f * (sc * (1.0f / 255.0f)) + s_bias[o];
}

extern "C" void kernel_launch(void* const* d_in, const int* in_sizes, int n_in,
                              void* d_out, int out_size, void* d_ws, size_t ws_size,
                              hipStream_t stream) {
    const float* x     = (const float*)d_in[0];
    const float* wgt   = (const float*)d_in[1];
    const float* cbias = (const float*)d_in[2];
    const float* pmin  = (const float*)d_in[3];
    const float* pmax  = (const float*)d_in[4];
    const float* ptbl  = (const float*)d_in[5];
    const int*   ridx  = (const int*)d_in[6];
    float* out = (float*)d_out;

    k_fused<<<512, 1024, 0, stream>>>(x, wgt, cbias, pmin, pmax, ptbl, ridx, out);
}

// Round 7
// 38.266 us; speedup vs baseline: 1.3794x; 1.3794x over previous
//
#include <hip/hip_runtime.h>

typedef unsigned int uint;

// Problem constants (from setup_inputs)
#define B_     2
#define C_     16
#define H_     66
#define W_     66
#define O_     64
#define CKK    144
#define NCH    36          // CKK/4
#define DIM    64          // output spatial
#define L_     4096        // DIM*DIM
#define N_     8192        // B_*L_
#define PLANE  524288      // N_*O_  (elements between (c,s) planes of rand_idx)
#define TSTR   1024        // fp16 table row stride (pow2: shift-only addressing)
#define TROWS  61          // rows 0..60; rows 0..7 zeroed (sign(Q)==0 there)
#define TCOLS  1000

typedef _Float16 h4 __attribute__((ext_vector_type(4)));

// dot4: sum of the 4 bytes of (xv & mask)  == dot(Xq_chunk, wmask)
__device__ __forceinline__ uint dot4(uint xv, uint m) {
#if __has_builtin(__builtin_amdgcn_sad_u8)
    return __builtin_amdgcn_sad_u8(xv & m, 0u, 0u);   // full-rate byte-sum
#else
    return ((xv & m) * 0x01010101u) >> 24;
#endif
}

// ---- prefetch group: 4 chunks x 2 signs x 2 streams = 16 dword loads ------
__device__ __forceinline__ void loadg(int (&buf)[16],
                                      const int* __restrict__ rp0,
                                      const int* __restrict__ rp1, int c0) {
#pragma unroll
    for (int j = 0; j < 4; ++j) {
        int c = c0 + j;
        buf[4 * j + 0] = rp0[(2 * c)     * PLANE];
        buf[4 * j + 1] = rp0[(2 * c + 1) * PLANE];
        buf[4 * j + 2] = rp1[(2 * c)     * PLANE];
        buf[4 * j + 3] = rp1[(2 * c + 1) * PLANE];
    }
}

// ---- consume one group: dot4 masks + 4 unconditional LDS gathers per j ----
__device__ __forceinline__ void procg(const int (&buf)[16],
                                      const uint*  __restrict__ xq0,
                                      const uint*  __restrict__ xq1,
                                      const uint2* __restrict__ sw,
                                      const _Float16* __restrict__ tbl,
                                      int c0, int o,
                                      float& sum0, float& sum1) {
#pragma unroll
    for (int j = 0; j < 4; ++j) {
        int c = c0 + j;
        uint xv0 = xq0[c];                  // wave-uniform LDS broadcast
        uint xv1 = xq1[c];
        uint2 m  = sw[c * O_ + o];          // ds_read_b64, 2-way (free)
        uint yp0 = dot4(xv0, m.x);
        uint ym0 = dot4(xv0, m.y);
        uint yp1 = dot4(xv1, m.x);
        uint ym1 = dot4(xv1, m.y);
        sum0 += (float)tbl[(yp0 << 10) + buf[4 * j + 0]];   // rows 0..7 zeroed
        sum0 -= (float)tbl[(ym0 << 10) + buf[4 * j + 1]];
        sum1 += (float)tbl[(yp1 << 10) + buf[4 * j + 2]];
        sum1 -= (float)tbl[(ym1 << 10) + buf[4 * j + 3]];
    }
}

__launch_bounds__(1024)
__global__ void k_fused(const float* __restrict__ x,
                        const float* __restrict__ wgt,
                        const float* __restrict__ cbias,
                        const float* __restrict__ pmin,
                        const float* __restrict__ pmax,
                        const float* __restrict__ ptbl,
                        const int*   __restrict__ ridx,
                        float* __restrict__ out) {
    __shared__ __align__(16) _Float16 tbl[TROWS * TSTR];  // 124,928 B
    __shared__ uint2 s_w[NCH * O_];                       //  18,432 B
    __shared__ float s_bias[O_];                          //     256 B
    __shared__ uint  s_xq[2][16 * NCH];                   //   4,608 B
    // total 148,224 B -> 1 block/CU, 16 waves

    const int tid = threadIdx.x;
    const float mn = pmin[0];
    const float sc = pmax[0] - mn;

    // ---- issue 4-deep index prefetch FIRST (oldest in vmcnt queue) ----
    const int o  = tid & 63;
    const int nl = tid >> 6;                   // 0..15
    const int n0 = blockIdx.x * 16 + nl;       // batch 0
    const int n1 = n0 + 4096;                  // batch 1
    const int* rp0 = ridx + n0 * O_ + o;
    const int* rp1 = ridx + n1 * O_ + o;
    int A[16], Bb[16], Cc[16], Dd[16];
    loadg(A,  rp0, rp1, 0);
    loadg(Bb, rp0, rp1, 4);
    loadg(Cc, rp0, rp1, 8);
    loadg(Dd, rp0, rp1, 12);

    // ---- Phase 0a: zero entire table (rows 0..7 + row pads) ----
    {
        uint4 z; z.x = z.y = z.z = z.w = 0u;
        uint4* zp = (uint4*)tbl;
        for (int q = tid; q < (TROWS * TSTR) / 8; q += 1024) zp[q] = z;
    }
    __syncthreads();
    // ---- Phase 0b: rows 8..60 -> fp16 LDS at stride 1024 ----
    for (int q = tid; q < 53 * 250; q += 1024) {           // 250 float4 per row
        int r = q / 250, k = q - r * 250;
        float4 v = *(const float4*)(ptbl + (8 + r) * TCOLS + k * 4);
        h4 hh = { (_Float16)v.x, (_Float16)v.y, (_Float16)v.z, (_Float16)v.w };
        *(h4*)(tbl + (8 + r) * TSTR + k * 4) = hh;
    }
    // ---- Phase 0c: ternary weight masks [c][o] as uint2 ----
    for (int q = tid; q < NCH * O_; q += 1024) {
        int c = q >> 6, oo = q & 63;
        float4 v = *(const float4*)(wgt + oo * CKK + c * 4);
        uint pm = 0, nm = 0;
        if (v.x > 0.0f) pm |= 0x000000FFu; else if (v.x < 0.0f) nm |= 0x000000FFu;
        if (v.y > 0.0f) pm |= 0x0000FF00u; else if (v.y < 0.0f) nm |= 0x0000FF00u;
        if (v.z > 0.0f) pm |= 0x00FF0000u; else if (v.z < 0.0f) nm |= 0x00FF0000u;
        if (v.w > 0.0f) pm |= 0xFF000000u; else if (v.w < 0.0f) nm |= 0xFF000000u;
        s_w[q] = make_uint2(pm, nm);
    }
    // ---- Phase 0d: quantize both tiles' 32 patches into s_xq ----
    for (int i = tid; i < 2 * 16 * NCH; i += 1024) {
        int t  = i / (16 * NCH);
        int r  = i - t * (16 * NCH);
        int nl2 = r / NCH;
        int c2  = r - nl2 * NCH;
        int n2  = blockIdx.x * 16 + nl2 + t * 4096;
        int b2 = n2 >> 12, l2 = n2 & (L_ - 1);
        int h2 = l2 >> 6,  w2 = l2 & (DIM - 1);
        uint packed = 0;
#pragma unroll
        for (int k = 0; k < 4; ++k) {
            int j  = c2 * 4 + k;
            int ci = j / 9;
            int r2 = j - ci * 9;
            int kh = r2 / 3;
            int kw = r2 - kh * 3;
            float v = x[((b2 * C_ + ci) * H_ + (h2 + kh)) * W_ + (w2 + kw)];
            float t2 = (v - mn) / sc * 15.0f;              // jax f32 op order
            float q = fminf(fmaxf(rintf(t2), 0.0f), 15.0f);
            packed |= ((uint)q) << (8 * k);
        }
        s_xq[t][r] = packed;
    }
    // ---- Phase 0e: bias from wgt (threads 0..63, L2-hot) ----
    if (tid < O_) {
        int sw = 0;
        for (int j = 0; j < CKK; ++j) {
            float v = wgt[tid * CKK + j];
            sw += (v > 0.0f) - (v < 0.0f);
        }
        s_bias[tid] = mn * (float)sw + cbias[tid];
    }
    __syncthreads();

    // ---- main: dual-stream, 4-deep (64 outstanding dword instrs/wave) ----
    const uint* xq0 = &s_xq[0][nl * NCH];
    const uint* xq1 = &s_xq[1][nl * NCH];
    const float bo  = s_bias[o];
    float sum0 = 0.0f, sum1 = 0.0f;

    procg(A,  xq0, xq1, s_w, tbl,  0, o, sum0, sum1); loadg(A,  rp0, rp1, 16);
    procg(Bb, xq0, xq1, s_w, tbl,  4, o, sum0, sum1); loadg(Bb, rp0, rp1, 20);
    procg(Cc, xq0, xq1, s_w, tbl,  8, o, sum0, sum1); loadg(Cc, rp0, rp1, 24);
    procg(Dd, xq0, xq1, s_w, tbl, 12, o, sum0, sum1); loadg(Dd, rp0, rp1, 28);
    procg(A,  xq0, xq1, s_w, tbl, 16, o, sum0, sum1); loadg(A,  rp0, rp1, 32);
    procg(Bb, xq0, xq1, s_w, tbl, 20, o, sum0, sum1);
    procg(Cc, xq0, xq1, s_w, tbl, 24, o, sum0, sum1);
    procg(Dd, xq0, xq1, s_w, tbl, 28, o, sum0, sum1);
    procg(A,  xq0, xq1, s_w, tbl, 32, o, sum0, sum1);

    // out[b][o][l]: n0 -> b=0,l=n0 ; n1 -> b=1,l=n1-4096
    out[o * L_ + n0]                     = sum0 * sc + bo;
    out[(O_ + o) * L_ + (n1 & (L_ - 1))] = sum1 * sc + bo;
}

extern "C" void kernel_launch(void* const* d_in, const int* in_sizes, int n_in,
                              void* d_out, int out_size, void* d_ws, size_t ws_size,
                              hipStream_t stream) {
    const float* x     = (const float*)d_in[0];
    const float* wgt   = (const float*)d_in[1];
    const float* cbias = (const float*)d_in[2];
    const float* pmin  = (const float*)d_in[3];
    const float* pmax  = (const float*)d_in[4];
    const float* ptbl  = (const float*)d_in[5];
    const int*   ridx  = (const int*)d_in[6];
    float* out = (float*)d_out;

    k_fused<<<256, 1024, 0, stream>>>(x, wgt, cbias, pmin, pmax, ptbl, ridx, out);
}

// Round 8
// 38.136 us; speedup vs baseline: 1.3841x; 1.0034x over previous
//
#include <hip/hip_runtime.h>

typedef unsigned int uint;

// Problem constants (from setup_inputs)
#define B_     2
#define C_     16
#define H_     66
#define W_     66
#define O_     64
#define CKK    144
#define NCH    36          // CKK/4
#define DIM    64          // output spatial
#define L_     4096        // DIM*DIM
#define N_     8192        // B_*L_
#define PLANE  524288      // N_*O_  (elements between (c,s) planes of rand_idx)
#define TSTR   1024        // fp16 table row stride (pow2: shift-only addressing)
#define TROWS  61          // rows 0..60; rows 0..7 zeroed (sign(Q)==0 there)
#define TCOLS  1000

typedef _Float16 h4 __attribute__((ext_vector_type(4)));

// ---- prefetch group: 4 chunks x 2 signs x 2 streams = 16 dword loads ------
__device__ __forceinline__ void loadg(int (&buf)[16],
                                      const int* __restrict__ rp0,
                                      const int* __restrict__ rp1, int c0) {
#pragma unroll
    for (int j = 0; j < 4; ++j) {
        int c = c0 + j;
        buf[4 * j + 0] = rp0[(2 * c)     * PLANE];
        buf[4 * j + 1] = rp0[(2 * c + 1) * PLANE];
        buf[4 * j + 2] = rp1[(2 * c)     * PLANE];
        buf[4 * j + 3] = rp1[(2 * c + 1) * PLANE];
    }
}

// ---- consume one group: dot4 masks + 4 unconditional LDS gathers per j ----
__device__ __forceinline__ void procg(const int (&buf)[16],
                                      const uint*  __restrict__ xq0,
                                      const uint*  __restrict__ xq1,
                                      const uint2* __restrict__ sw,
                                      const _Float16* __restrict__ tbl,
                                      int c0, int o,
                                      float& sum0, float& sum1) {
#pragma unroll
    for (int j = 0; j < 4; ++j) {
        int c = c0 + j;
        uint xv0 = xq0[c];                  // wave-uniform LDS broadcast
        uint xv1 = xq1[c];
        uint2 m  = sw[c * O_ + o];          // ds_read_b64, 2-way (free)
        uint yp0 = ((xv0 & m.x) * 0x01010101u) >> 24;
        uint ym0 = ((xv0 & m.y) * 0x01010101u) >> 24;
        uint yp1 = ((xv1 & m.x) * 0x01010101u) >> 24;
        uint ym1 = ((xv1 & m.y) * 0x01010101u) >> 24;
        sum0 += (float)tbl[(yp0 << 10) + buf[4 * j + 0]];   // rows 0..7 zeroed
        sum0 -= (float)tbl[(ym0 << 10) + buf[4 * j + 1]];
        sum1 += (float)tbl[(yp1 << 10) + buf[4 * j + 2]];
        sum1 -= (float)tbl[(ym1 << 10) + buf[4 * j + 3]];
    }
}

__launch_bounds__(1024)
__global__ void k_fused(const float* __restrict__ x,
                        const float* __restrict__ wgt,
                        const float* __restrict__ cbias,
                        const float* __restrict__ pmin,
                        const float* __restrict__ pmax,
                        const float* __restrict__ ptbl,
                        const int*   __restrict__ ridx,
                        float* __restrict__ out) {
    __shared__ __align__(16) _Float16 tbl[TROWS * TSTR];  // 124,928 B
    __shared__ uint2 s_w[NCH * O_];                       //  18,432 B
    __shared__ float s_bias[O_];                          //     256 B
    __shared__ uint  s_xq[2][16 * NCH];                   //   4,608 B
    // total 148,224 B -> 1 block/CU, 16 waves

    const int tid = threadIdx.x;
    const float mn = pmin[0];
    const float sc = pmax[0] - mn;

    // ---- issue 2-deep index prefetch FIRST (oldest in vmcnt queue) ----
    const int o  = tid & 63;
    const int nl = tid >> 6;                   // 0..15
    const int n0 = blockIdx.x * 16 + nl;       // batch 0
    const int n1 = n0 + 4096;                  // batch 1
    const int* rp0 = ridx + n0 * O_ + o;
    const int* rp1 = ridx + n1 * O_ + o;
    int A[16], Bb[16];
    loadg(A,  rp0, rp1, 0);
    loadg(Bb, rp0, rp1, 4);

    // ---- Phase 0a: zero entire table (rows 0..7 + row pads) ----
    {
        uint4 z; z.x = z.y = z.z = z.w = 0u;
        uint4* zp = (uint4*)tbl;
        for (int q = tid; q < (TROWS * TSTR) / 8; q += 1024) zp[q] = z;
    }
    __syncthreads();
    // ---- Phase 0b: rows 8..60 -> fp16 LDS at stride 1024 ----
    for (int q = tid; q < 53 * 250; q += 1024) {           // 250 float4 per row
        int r = q / 250, k = q - r * 250;
        float4 v = *(const float4*)(ptbl + (8 + r) * TCOLS + k * 4);
        h4 hh = { (_Float16)v.x, (_Float16)v.y, (_Float16)v.z, (_Float16)v.w };
        *(h4*)(tbl + (8 + r) * TSTR + k * 4) = hh;
    }
    // ---- Phase 0c: ternary weight masks [c][o] as uint2 ----
    for (int q = tid; q < NCH * O_; q += 1024) {
        int c = q >> 6, oo = q & 63;
        float4 v = *(const float4*)(wgt + oo * CKK + c * 4);
        uint pm = 0, nm = 0;
        if (v.x > 0.0f) pm |= 0x000000FFu; else if (v.x < 0.0f) nm |= 0x000000FFu;
        if (v.y > 0.0f) pm |= 0x0000FF00u; else if (v.y < 0.0f) nm |= 0x0000FF00u;
        if (v.z > 0.0f) pm |= 0x00FF0000u; else if (v.z < 0.0f) nm |= 0x00FF0000u;
        if (v.w > 0.0f) pm |= 0xFF000000u; else if (v.w < 0.0f) nm |= 0xFF000000u;
        s_w[q] = make_uint2(pm, nm);
    }
    // ---- Phase 0d: quantize both tiles' 32 patches into s_xq ----
    for (int i = tid; i < 2 * 16 * NCH; i += 1024) {
        int t  = i / (16 * NCH);
        int r  = i - t * (16 * NCH);
        int nl2 = r / NCH;
        int c2  = r - nl2 * NCH;
        int n2  = blockIdx.x * 16 + nl2 + t * 4096;
        int b2 = n2 >> 12, l2 = n2 & (L_ - 1);
        int h2 = l2 >> 6,  w2 = l2 & (DIM - 1);
        uint packed = 0;
#pragma unroll
        for (int k = 0; k < 4; ++k) {
            int j  = c2 * 4 + k;
            int ci = j / 9;
            int r2 = j - ci * 9;
            int kh = r2 / 3;
            int kw = r2 - kh * 3;
            float v = x[((b2 * C_ + ci) * H_ + (h2 + kh)) * W_ + (w2 + kw)];
            float t2 = (v - mn) / sc * 15.0f;              // jax f32 op order
            float q = fminf(fmaxf(rintf(t2), 0.0f), 15.0f);
            packed |= ((uint)q) << (8 * k);
        }
        s_xq[t][r] = packed;
    }
    // ---- Phase 0e: bias from wgt (threads 0..63, L2-hot) ----
    if (tid < O_) {
        int sw = 0;
        for (int j = 0; j < CKK; ++j) {
            float v = wgt[tid * CKK + j];
            sw += (v > 0.0f) - (v < 0.0f);
        }
        s_bias[tid] = mn * (float)sw + cbias[tid];
    }
    __syncthreads();

    // ---- main: dual-stream, 2-deep ping-pong (32 outstanding dword instrs) ----
    const uint* xq0 = &s_xq[0][nl * NCH];
    const uint* xq1 = &s_xq[1][nl * NCH];
    const float bo  = s_bias[o];
    float sum0 = 0.0f, sum1 = 0.0f;

    procg(A,  xq0, xq1, s_w, tbl,  0, o, sum0, sum1); loadg(A,  rp0, rp1,  8);
    procg(Bb, xq0, xq1, s_w, tbl,  4, o, sum0, sum1); loadg(Bb, rp0, rp1, 12);
    procg(A,  xq0, xq1, s_w, tbl,  8, o, sum0, sum1); loadg(A,  rp0, rp1, 16);
    procg(Bb, xq0, xq1, s_w, tbl, 12, o, sum0, sum1); loadg(Bb, rp0, rp1, 20);
    procg(A,  xq0, xq1, s_w, tbl, 16, o, sum0, sum1); loadg(A,  rp0, rp1, 24);
    procg(Bb, xq0, xq1, s_w, tbl, 20, o, sum0, sum1); loadg(Bb, rp0, rp1, 28);
    procg(A,  xq0, xq1, s_w, tbl, 24, o, sum0, sum1); loadg(A,  rp0, rp1, 32);
    procg(Bb, xq0, xq1, s_w, tbl, 28, o, sum0, sum1);
    procg(A,  xq0, xq1, s_w, tbl, 32, o, sum0, sum1);

    // out[b][o][l]: n0 -> b=0,l=n0 ; n1 -> b=1,l=n1-4096
    out[o * L_ + n0]                     = sum0 * sc + bo;
    out[(O_ + o) * L_ + (n1 & (L_ - 1))] = sum1 * sc + bo;
}

extern "C" void kernel_launch(void* const* d_in, const int* in_sizes, int n_in,
                              void* d_out, int out_size, void* d_ws, size_t ws_size,
                              hipStream_t stream) {
    const float* x     = (const float*)d_in[0];
    const float* wgt   = (const float*)d_in[1];
    const float* cbias = (const float*)d_in[2];
    const float* pmin  = (const float*)d_in[3];
    const float* pmax  = (const float*)d_in[4];
    const float* ptbl  = (const float*)d_in[5];
    const int*   ridx  = (const int*)d_in[6];
    float* out = (float*)d_out;

    k_fused<<<256, 1024, 0, stream>>>(x, wgt, cbias, pmin, pmax, ptbl, ridx, out);
}